// Round 1
// baseline (205.440 us; speedup 1.0000x reference)
//
#include <hip/hip_runtime.h>

#define HH  512
#define WW  512
#define RAD 10
#define KK  21
#define SEG 64

// Fused separable Gaussian blur (21x21, sigma=3) with reflect padding.
// Vertical pass: per-thread register history of 21 raw rows (2 cols/thread).
// Horizontal pass: vblurred row staged in LDS (double-buffered, reflect-padded).
__global__ __launch_bounds__(256) void gauss_blur_kernel(
    const float* __restrict__ x, float* __restrict__ out)
{
    // g[d] = exp(-d^2/18), w = g / sum(g); 2D kernel = outer(w, w) exactly.
    const float w[KK] = {
        0.00051432f, 0.00147793f, 0.00380033f, 0.00874446f, 0.01800488f,
        0.03317359f, 0.05469399f, 0.08069227f, 0.10652936f, 0.12584957f,
        0.13303907f,
        0.12584957f, 0.10652936f, 0.08069227f, 0.05469399f, 0.03317359f,
        0.01800488f, 0.00874446f, 0.00380033f, 0.00147793f, 0.00051432f
    };

    // 532 used floats per buffer (512 + 2*10 reflect pad); 536 keeps 16B align.
    __shared__ __align__(16) float vbuf[2][536];

    const int t   = threadIdx.x;
    const int c0  = 2 * t;        // this thread's two columns: c0, c0+1
    const int c1  = c0 + 1;
    const int seg = blockIdx.x;   // row segment [y0, y0+SEG)
    const int img = blockIdx.y;   // b*C + c image index
    const int y0  = seg * SEG;

    const float* xim = x   + (size_t)img * (HH * WW);
    float*       oim = out + (size_t)img * (HH * WW);

    auto loadrow = [&](int r) -> float2 {
        // reflect ('even', no edge duplication): -k -> k ; 511+k -> 511-k
        int rr = r < 0 ? -r : (r > HH - 1 ? 2 * (HH - 1) - r : r);
        return *(const float2*)(xim + rr * WW + c0);
    };

    // Register ring: hist[i] = raw row (y - RAD + i) for current output row y.
    float2 hist[KK];

    #pragma unroll
    for (int i = 0; i < KK - 1; ++i)
        hist[i] = loadrow(y0 - RAD + i);

    float2 nxt = loadrow(y0 + RAD);

    for (int i2 = 0; i2 < SEG; ++i2) {
        const int y = y0 + i2;
        hist[KK - 1] = nxt;
        nxt = loadrow(y + RAD + 1);   // prefetch; reflect keeps it in-bounds

        // ---- vertical blur (registers only) ----
        float vx = 0.f, vy = 0.f;
        #pragma unroll
        for (int k = 0; k < KK; ++k) {
            vx += w[k] * hist[k].x;
            vy += w[k] * hist[k].y;
        }

        // ---- stage vblurred row to LDS with reflect pads in x ----
        float* vb = vbuf[i2 & 1];
        *(float2*)(vb + RAD + c0) = make_float2(vx, vy);
        // left pad: vb[RAD - k] = vblur[k], k = 1..RAD
        if (c0 >= 1 && c0 <= RAD) vb[RAD - c0] = vx;
        if (c1 <= RAD)            vb[RAD - c1] = vy;
        // right pad: vb[RAD + 2*(WW-1) - c] = vblur[c], c = WW-11 .. WW-2
        if (c0 >= WW - 11 && c0 <= WW - 2) vb[RAD + 2 * (WW - 1) - c0] = vx;
        if (c1 >= WW - 11 && c1 <= WW - 2) vb[RAD + 2 * (WW - 1) - c1] = vy;

        __syncthreads();   // one barrier/row; double buffer handles WAR hazard

        // ---- horizontal blur from LDS ----
        // window for cols {c0, c1}: vb[c0 .. c0+21]  (22 floats, 11 float2)
        const float* vr = vb + c0;   // (RAD + c0 - RAD)
        float wn[KK + 1];
        #pragma unroll
        for (int j = 0; j < 11; ++j) {
            float2 t2 = *(const float2*)(vr + 2 * j);
            wn[2 * j]     = t2.x;
            wn[2 * j + 1] = t2.y;
        }
        float acc0 = 0.f, acc1 = 0.f;
        #pragma unroll
        for (int j = 0; j < KK; ++j) {
            acc0 += w[j] * wn[j];
            acc1 += w[j] * wn[j + 1];
        }
        *(float2*)(oim + (size_t)y * WW + c0) = make_float2(acc0, acc1);

        // ---- slide history ----
        #pragma unroll
        for (int i = 0; i < KK - 1; ++i)
            hist[i] = hist[i + 1];
    }
}

extern "C" void kernel_launch(void* const* d_in, const int* in_sizes, int n_in,
                              void* d_out, int out_size, void* d_ws, size_t ws_size,
                              hipStream_t stream) {
    const float* x = (const float*)d_in[0];
    float* out = (float*)d_out;
    const int n_img = in_sizes[0] / (HH * WW);   // 32*3 = 96
    dim3 grid(HH / SEG, n_img);                  // (8, 96) = 768 blocks
    gauss_blur_kernel<<<grid, dim3(256), 0, stream>>>(x, out);
}

// Round 3
// 201.224 us; speedup vs baseline: 1.0209x; 1.0209x over previous
//
#include <hip/hip_runtime.h>

#define HH  512
#define WW  512
#define RAD 10
#define KK  21
#define SEG 16        // output rows per block
#define LSTRIDE 540   // LDS row stride in floats: 532 used (512 + 2*RAD pad),
                      // 540 keeps 16B alignment AND spreads b128 start banks
                      // over {0,4,...,28} -> uniform bank load, no conflicts

// Fused separable Gaussian blur (21x21, sigma=3), reflect padding.
// Phase 1: per-thread register sliding window over 36 raw rows -> 16 vblur
//          rows into LDS (reflect-padded in x). ONE barrier.
// Phase 2: threads remap to (row, 16-col group); 9x ds_read_b128 window,
//          horizontal sliding conv, float4 stores.
__global__ __launch_bounds__(256, 4) void gauss_blur_kernel(
    const float* __restrict__ x, float* __restrict__ out)
{
    // g[d] = exp(-d^2/18), w = g/sum(g); 2D kernel = outer(w,w) exactly.
    const float wt[KK] = {
        0.00051432f, 0.00147793f, 0.00380033f, 0.00874446f, 0.01800488f,
        0.03317359f, 0.05469399f, 0.08069227f, 0.10652936f, 0.12584957f,
        0.13303907f,
        0.12584957f, 0.10652936f, 0.08069227f, 0.05469399f, 0.03317359f,
        0.01800488f, 0.00874446f, 0.00380033f, 0.00147793f, 0.00051432f
    };

    __shared__ __align__(16) float vbuf[SEG * LSTRIDE];   // 34.56 KB

    const int t   = threadIdx.x;
    const int c0  = 2 * t;          // phase-1 columns: c0, c0+1
    const int c1  = c0 + 1;
    const int y0  = blockIdx.x * SEG;
    const int img = blockIdx.y;

    const float* xim = x   + (size_t)img * (HH * WW);
    float*       oim = out + (size_t)img * (HH * WW);

    auto loadrow = [&](int r) -> float2 {
        int rr = r < 0 ? -r : (r > HH - 1 ? 2 * (HH - 1) - r : r);
        return *(const float2*)(xim + rr * WW + c0);
    };

    // ---------------- Phase 1: vertical blur ----------------
    float2 hist[KK];
    #pragma unroll
    for (int i = 0; i < KK; ++i)
        hist[i] = loadrow(y0 - RAD + i);

    #pragma unroll
    for (int r = 0; r < SEG; ++r) {
        float vx = 0.f, vy = 0.f;
        #pragma unroll
        for (int k = 0; k < KK; ++k) {
            vx += wt[k] * hist[k].x;
            vy += wt[k] * hist[k].y;
        }
        float* vb = vbuf + r * LSTRIDE;
        *(float2*)(vb + RAD + c0) = make_float2(vx, vy);
        // reflect pads in x
        if (c0 >= 1 && c0 <= RAD)           vb[RAD - c0] = vx;
        if (c1 <= RAD)                      vb[RAD - c1] = vy;
        if (c0 >= WW - 11 && c0 <= WW - 2)  vb[RAD + 2 * (WW - 1) - c0] = vx;
        if (c1 >= WW - 11 && c1 <= WW - 2)  vb[RAD + 2 * (WW - 1) - c1] = vy;

        if (r < SEG - 1) {
            #pragma unroll
            for (int i = 0; i < KK - 1; ++i) hist[i] = hist[i + 1];  // renamed, no movs (unrolled)
            hist[KK - 1] = loadrow(y0 + r + 1 + RAD);
        }
    }

    __syncthreads();   // the only barrier

    // ---------------- Phase 2: horizontal blur ----------------
    // 512 tasks: task -> (row r = task & 15, col-group q = task >> 4, 16 cols)
    #pragma unroll
    for (int task = 0; task < 2; ++task) {
        const int tid = t + task * 256;
        const int r   = tid & (SEG - 1);
        const int q   = tid >> 4;                    // 0..31
        // padded window start = RAD + (q*16 - RAD) = q*16  -> 16B aligned
        const float* vr = vbuf + r * LSTRIDE + q * 16;

        float wnd[36];
        #pragma unroll
        for (int j = 0; j < 9; ++j) {
            float4 v4 = *(const float4*)(vr + 4 * j);
            wnd[4*j]   = v4.x; wnd[4*j+1] = v4.y;
            wnd[4*j+2] = v4.z; wnd[4*j+3] = v4.w;
        }

        float acc[16];
        #pragma unroll
        for (int j = 0; j < 16; ++j) {
            float s = 0.f;
            #pragma unroll
            for (int k = 0; k < KK; ++k)
                s += wt[k] * wnd[j + k];
            acc[j] = s;
        }

        float* op = oim + (size_t)(y0 + r) * WW + q * 16;
        #pragma unroll
        for (int j = 0; j < 4; ++j)
            *(float4*)(op + 4 * j) =
                make_float4(acc[4*j], acc[4*j+1], acc[4*j+2], acc[4*j+3]);
    }
}

extern "C" void kernel_launch(void* const* d_in, const int* in_sizes, int n_in,
                              void* d_out, int out_size, void* d_ws, size_t ws_size,
                              hipStream_t stream) {
    const float* x = (const float*)d_in[0];
    float* out = (float*)d_out;
    const int n_img = in_sizes[0] / (HH * WW);     // 32*3 = 96
    dim3 grid(HH / SEG, n_img);                    // (32, 96) = 3072 blocks
    gauss_blur_kernel<<<grid, dim3(256), 0, stream>>>(x, out);
}

// Round 4
// 189.128 us; speedup vs baseline: 1.0862x; 1.0640x over previous
//
#include <hip/hip_runtime.h>

#define HH  512
#define WW  512
#define RAD 10
#define KK  21
#define SEG 16        // output rows per block
#define NROWS (SEG + 2 * RAD)   // 36 raw rows per block
#define LSTRIDE 540   // LDS row stride (floats): 532 used, 540 = 16B-aligned,
                      // mod 32 = 28 -> b128 start banks uniform, ~conflict-free

// Fused separable Gaussian blur (21x21, sigma=3), reflect padding.
// Phase 1: preload ALL 36 raw rows (2 cols/thread) into registers -> 36
//          independent loads in flight (deep MLP, hides ~900cyc HBM latency),
//          then 16 vblur rows into LDS (reflect-padded in x). ONE barrier.
// Phase 2: threads remap to (row, 16-col group); 9x ds_read_b128 window,
//          horizontal sliding conv, float4 stores.
// LDS 34.8KB -> 4 blocks/CU (16 waves); <=128 VGPR keeps that occupancy.
__global__ __launch_bounds__(256, 4) void gauss_blur_kernel(
    const float* __restrict__ x, float* __restrict__ out)
{
    // g[d] = exp(-d^2/18), w = g/sum(g); 2D kernel = outer(w,w) exactly.
    const float wt[KK] = {
        0.00051432f, 0.00147793f, 0.00380033f, 0.00874446f, 0.01800488f,
        0.03317359f, 0.05469399f, 0.08069227f, 0.10652936f, 0.12584957f,
        0.13303907f,
        0.12584957f, 0.10652936f, 0.08069227f, 0.05469399f, 0.03317359f,
        0.01800488f, 0.00874446f, 0.00380033f, 0.00147793f, 0.00051432f
    };

    __shared__ __align__(16) float vbuf[SEG * LSTRIDE];   // 34.56 KB

    const int t   = threadIdx.x;
    const int c0  = 2 * t;          // phase-1 columns: c0, c0+1
    const int c1  = c0 + 1;
    const int y0  = blockIdx.x * SEG;
    const int img = blockIdx.y;

    const float* xim = x   + (size_t)img * (HH * WW);
    float*       oim = out + (size_t)img * (HH * WW);

    // ---------------- Phase 1: preload all raw rows (36 loads in flight) ----
    float2 rows[NROWS];
    #pragma unroll
    for (int i = 0; i < NROWS; ++i) {
        int r  = y0 - RAD + i;
        int rr = r < 0 ? -r : (r > HH - 1 ? 2 * (HH - 1) - r : r);
        rows[i] = *(const float2*)(xim + rr * WW + c0);
    }

    // ---------------- vertical blur -> LDS ----------------
    #pragma unroll
    for (int r = 0; r < SEG; ++r) {
        float vx = 0.f, vy = 0.f;
        #pragma unroll
        for (int k = 0; k < KK; ++k) {
            vx = fmaf(wt[k], rows[r + k].x, vx);
            vy = fmaf(wt[k], rows[r + k].y, vy);
        }
        float* vb = vbuf + r * LSTRIDE;
        *(float2*)(vb + RAD + c0) = make_float2(vx, vy);
        // reflect pads in x
        if (c0 >= 1 && c0 <= RAD)           vb[RAD - c0] = vx;
        if (c1 <= RAD)                      vb[RAD - c1] = vy;
        if (c0 >= WW - 11 && c0 <= WW - 2)  vb[RAD + 2 * (WW - 1) - c0] = vx;
        if (c1 >= WW - 11 && c1 <= WW - 2)  vb[RAD + 2 * (WW - 1) - c1] = vy;
    }

    __syncthreads();   // the only barrier

    // ---------------- Phase 2: horizontal blur ----------------
    // 512 tasks: task -> (row r = task & 15, col-group q = task >> 4, 16 cols)
    #pragma unroll
    for (int task = 0; task < 2; ++task) {
        const int tid = t + task * 256;
        const int r   = tid & (SEG - 1);
        const int q   = tid >> 4;                    // 0..31
        // padded window start = RAD + (q*16 - RAD) = q*16  -> 16B aligned
        const float* vr = vbuf + r * LSTRIDE + q * 16;

        float wnd[36];
        #pragma unroll
        for (int j = 0; j < 9; ++j) {
            float4 v4 = *(const float4*)(vr + 4 * j);
            wnd[4*j]   = v4.x; wnd[4*j+1] = v4.y;
            wnd[4*j+2] = v4.z; wnd[4*j+3] = v4.w;
        }

        float acc[16];
        #pragma unroll
        for (int j = 0; j < 16; ++j) {
            float s = 0.f;
            #pragma unroll
            for (int k = 0; k < KK; ++k)
                s = fmaf(wt[k], wnd[j + k], s);
            acc[j] = s;
        }

        float* op = oim + (size_t)(y0 + r) * WW + q * 16;
        #pragma unroll
        for (int j = 0; j < 4; ++j)
            *(float4*)(op + 4 * j) =
                make_float4(acc[4*j], acc[4*j+1], acc[4*j+2], acc[4*j+3]);
    }
}

extern "C" void kernel_launch(void* const* d_in, const int* in_sizes, int n_in,
                              void* d_out, int out_size, void* d_ws, size_t ws_size,
                              hipStream_t stream) {
    const float* x = (const float*)d_in[0];
    float* out = (float*)d_out;
    const int n_img = in_sizes[0] / (HH * WW);     // 32*3 = 96
    dim3 grid(HH / SEG, n_img);                    // (32, 96) = 3072 blocks
    gauss_blur_kernel<<<grid, dim3(256), 0, stream>>>(x, out);
}